// Round 3
// baseline (43132.657 us; speedup 1.0000x reference)
//
#include <hip/hip_runtime.h>

#define KNBR 32
#define NCELL 4096      // 16^3 Morton cells
#define FT 1024         // fps threads
#define FP 20           // points per fps thread (1024*20 = 20480 >= 20000)

// Reference-matching squared distance: ((dx*dx + dy*dy) + dz*dz), no FMA contraction.
__device__ __forceinline__ float sq_dist_nofma(float px, float py, float pz,
                                               float cx, float cy, float cz) {
    float dx = __fsub_rn(px, cx);
    float dy = __fsub_rn(py, cy);
    float dz = __fsub_rn(pz, cz);
    return __fadd_rn(__fadd_rn(__fmul_rn(dx, dx), __fmul_rn(dy, dy)), __fmul_rn(dz, dz));
}

// spread 4 bits: bit b -> bit 3b
__device__ __forceinline__ unsigned spread4(unsigned v) {
    return (v & 1u) | ((v & 2u) << 2) | ((v & 4u) << 4) | ((v & 8u) << 6);
}

// K1: AoS coords -> SoA + norms + Morton cell id + within-cell rank (counting-sort pass 1)
__global__ void prep_kernel(const float* __restrict__ coord, int N,
                            float* __restrict__ sx, float* __restrict__ sy,
                            float* __restrict__ sz, float* __restrict__ sn,
                            int* __restrict__ cell, int* __restrict__ rank,
                            int* __restrict__ hist) {
    int i = blockIdx.x * blockDim.x + threadIdx.x;
    if (i < N) {
        float x = coord[3 * i + 0];
        float y = coord[3 * i + 1];
        float z = coord[3 * i + 2];
        sx[i] = x; sy[i] = y; sz[i] = z;
        sn[i] = __fadd_rn(__fadd_rn(__fmul_rn(x, x), __fmul_rn(y, y)), __fmul_rn(z, z));
        int ix = (int)(x * 16.0f); ix = ix < 0 ? 0 : (ix > 15 ? 15 : ix);
        int iy = (int)(y * 16.0f); iy = iy < 0 ? 0 : (iy > 15 ? 15 : iy);
        int iz = (int)(z * 16.0f); iz = iz < 0 ? 0 : (iz > 15 ? 15 : iz);
        unsigned mc = spread4(ix) | (spread4(iy) << 1) | (spread4(iz) << 2);
        cell[i] = (int)mc;
        rank[i] = atomicAdd(&hist[mc], 1);
    }
}

// K2: exclusive scan of 4096-bin histogram (one block, 4 bins/thread)
__global__ __launch_bounds__(1024) void scan_kernel(const int* __restrict__ hist,
                                                    int* __restrict__ cellstart) {
    __shared__ int buf[1024];
    int t = threadIdx.x;
    int h0 = hist[4 * t], h1 = hist[4 * t + 1], h2 = hist[4 * t + 2], h3 = hist[4 * t + 3];
    int s = h0 + h1 + h2 + h3;
    buf[t] = s;
    __syncthreads();
    for (int off = 1; off < 1024; off <<= 1) {
        int v = (t >= off) ? buf[t - off] : 0;
        __syncthreads();
        buf[t] += v;
        __syncthreads();
    }
    int ex = buf[t] - s;   // exclusive prefix of this thread's 4-bin group
    cellstart[4 * t]     = ex;
    cellstart[4 * t + 1] = ex + h0;
    cellstart[4 * t + 2] = ex + h0 + h1;
    cellstart[4 * t + 3] = ex + h0 + h1 + h2;
}

// K3: scatter points into Morton order (counting-sort pass 2)
__global__ void scatter_kernel(const float* __restrict__ sx, const float* __restrict__ sy,
                               const float* __restrict__ sz,
                               const int* __restrict__ cell, const int* __restrict__ rank,
                               const int* __restrict__ cellstart, int N,
                               float* __restrict__ rx, float* __restrict__ ry,
                               float* __restrict__ rz, int* __restrict__ rorig) {
    int i = blockIdx.x * blockDim.x + threadIdx.x;
    if (i < N) {
        int pos = cellstart[cell[i]] + rank[i];
        rx[pos] = sx[i]; ry[pos] = sy[i]; rz[pos] = sz[i];
        rorig[pos] = i;
    }
}

// K4: farthest point sampling, single block.
// - points Morton-sorted; each thread owns FP contiguous points + a bounding sphere
// - per-step: skip whole thread's update if (D - r_t)^2 > max md in thread (conservative)
// - single barrier per step: owner lane writes (v,i,x,y,z) tuple; all threads pick winner
__global__ __launch_bounds__(FT) __attribute__((amdgpu_waves_per_eu(4, 4)))
void fps_kernel(const float* __restrict__ rx, const float* __restrict__ ry,
                const float* __restrict__ rz, const int* __restrict__ rorig,
                const float* __restrict__ sx, const float* __restrict__ sy,
                const float* __restrict__ sz,
                int N, int n_dst, int* __restrict__ out_idx) {
    const int NW = FT / 64;
    __shared__ float tup[2][NW][8];   // [parity][wave][v, i(bits), x, y, z, ...]

    const int tid = threadIdx.x;
    const int wv  = tid >> 6;
    const int base = tid * FP;
    int npts = N - base; npts = npts < 0 ? 0 : (npts > FP ? FP : npts);

    float px[FP], py[FP], pz[FP], md[FP]; int og[FP];
    #pragma unroll
    for (int j = 0; j < FP; ++j) {
        if (j < npts) {
            px[j] = rx[base + j]; py[j] = ry[base + j]; pz[j] = rz[base + j];
            og[j] = rorig[base + j];
        } else { px[j] = 0.f; py[j] = 0.f; pz[j] = 0.f; og[j] = 0x7fffffff; }
    }

    // bounding sphere of this thread's points (conservative; fast math fine)
    float mnx = 1e30f, mny = 1e30f, mnz = 1e30f, mxx = -1e30f, mxy = -1e30f, mxz = -1e30f;
    #pragma unroll
    for (int j = 0; j < FP; ++j) if (j < npts) {
        mnx = fminf(mnx, px[j]); mxx = fmaxf(mxx, px[j]);
        mny = fminf(mny, py[j]); mxy = fmaxf(mxy, py[j]);
        mnz = fminf(mnz, pz[j]); mxz = fmaxf(mxz, pz[j]);
    }
    float ctx = 0.5f * (mnx + mxx), cty = 0.5f * (mny + mxy), ctz = 0.5f * (mnz + mxz);
    float r2 = 0.f;
    #pragma unroll
    for (int j = 0; j < FP; ++j) if (j < npts) {
        float dx = px[j] - ctx, dy = py[j] - cty, dz = pz[j] - ctz;
        r2 = fmaxf(r2, dx * dx + dy * dy + dz * dz);
    }
    float rt = sqrtf(r2) * 1.0001f + 1e-7f;

    // init md vs original point 0
    float c0x = sx[0], c0y = sy[0], c0z = sz[0];
    float bv = -3e38f, bx = 0.f, by = 0.f, bz = 0.f; int bi = 0x7fffffff;
    #pragma unroll
    for (int j = 0; j < FP; ++j) if (j < npts) {
        float d = sq_dist_nofma(px[j], py[j], pz[j], c0x, c0y, c0z);
        md[j] = d;
        if (d > bv || (d == bv && og[j] < bi)) { bv = d; bi = og[j]; bx = px[j]; by = py[j]; bz = pz[j]; }
    }
    float thr2 = -1.f;
    if (npts > 0) { float t0 = sqrtf(fmaxf(bv, 0.f)) * 1.0001f + rt; thr2 = t0 * t0 * 1.0002f + 1e-12f; }
    if (tid == 0) out_idx[0] = 0;

    int par = 0;
    for (int s = 1; s < n_dst; ++s) {
        // wave argmax of (bv, bi) with first-original-index tie-break
        float v = bv; int i = bi;
        #pragma unroll
        for (int off = 32; off; off >>= 1) {
            float v2 = __shfl_xor(v, off, 64);
            int   i2 = __shfl_xor(i, off, 64);
            if (v2 > v || (v2 == v && i2 < i)) { v = v2; i = i2; }
        }
        // owner lane (unique: orig indices are unique) writes the wave tuple incl. coords
        if (bi == i) {
            tup[par][wv][0] = v;
            tup[par][wv][1] = __int_as_float(i);
            tup[par][wv][2] = bx; tup[par][wv][3] = by; tup[par][wv][4] = bz;
        }
        __syncthreads();
        // every thread picks the global winner from NW tuples (LDS broadcast reads)
        float Wv = -3e38f; int Wi = 0x7fffffff; int Ww = 0;
        #pragma unroll
        for (int w = 0; w < NW; ++w) {
            float tv = tup[par][w][0];
            int   ti = __float_as_int(tup[par][w][1]);
            if (tv > Wv || (tv == Wv && ti < Wi)) { Wv = tv; Wi = ti; Ww = w; }
        }
        float ncx = tup[par][Ww][2], ncy = tup[par][Ww][3], ncz = tup[par][Ww][4];
        if (tid == 0) out_idx[s] = Wi;
        par ^= 1;   // next step writes the other buffer; no second barrier needed

        // spatial prune: skip if no point in this thread can have md reduced
        float Dx = ncx - ctx, Dy = ncy - cty, Dz = ncz - ctz;
        float D2 = Dx * Dx + Dy * Dy + Dz * Dz;
        if (npts > 0 && D2 <= thr2) {
            bv = -3e38f; bi = 0x7fffffff;
            #pragma unroll
            for (int j = 0; j < FP; ++j) if (j < npts) {
                float d = sq_dist_nofma(px[j], py[j], pz[j], ncx, ncy, ncz);
                float m = fminf(md[j], d);
                md[j] = m;
                if (m > bv || (m == bv && og[j] < bi)) { bv = m; bi = og[j]; bx = px[j]; by = py[j]; bz = pz[j]; }
            }
            float t0 = sqrtf(bv) * 1.0001f + rt;   // bv >= 0 here
            thr2 = t0 * t0 * 1.0002f + 1e-12f;
        }
        // skipped threads keep valid (bv,bi,bx,by,bz,thr2): their md is provably unchanged
    }
}

// K5: ball query, one wave per dst. First K in-radius src indices in ascending order.
// d2 replicates reference: (dn + sn) - 2*(fma-chain inner product)  [BLAS-style matmul].
__global__ void ball_kernel(const float* __restrict__ sx, const float* __restrict__ sy,
                            const float* __restrict__ sz, const float* __restrict__ sn,
                            const int* __restrict__ idx,
                            const float* __restrict__ coord, const int* __restrict__ batch,
                            int N, int n_dst,
                            float* __restrict__ out_coord, float* __restrict__ out_esrc,
                            float* __restrict__ out_edst, float* __restrict__ out_deg,
                            float* __restrict__ out_batch,
                            int* __restrict__ nbr_i, int* __restrict__ deg_i) {
    const int d    = blockIdx.x;
    const int lane = threadIdx.x;   // block of 64
    __shared__ int nbr[KNBR];

    const int id = idx[d];
    const float cx = sx[id], cy = sy[id], cz = sz[id];
    const float dn = sn[id];
    const float RR = (float)(0.08 * 0.08);

    int cnt = 0;
    for (int base = 0; base < N && cnt < KNBR; base += 64) {
        int i = base + lane;
        bool in = false;
        if (i < N) {
            float t     = __fmul_rn(sx[i], cx);
            float inner = __fmaf_rn(sy[i], cy, t);
            inner       = __fmaf_rn(sz[i], cz, inner);
            float d2    = __fsub_rn(__fadd_rn(dn, sn[i]), __fmul_rn(2.0f, inner));
            in = (d2 <= RR);
        }
        unsigned long long m = __ballot(in);
        int pos = cnt + __popcll(m & ((1ull << lane) - 1ull));
        if (in && pos < KNBR) nbr[pos] = i;
        cnt += (int)__popcll(m);
    }
    __syncthreads();

    int deg = cnt < KNBR ? cnt : KNBR;
    if (lane < KNBR) {
        int e = (lane < deg) ? nbr[lane] : -1;
        out_esrc[d * KNBR + lane] = (float)e;
        out_edst[d * KNBR + lane] = (float)((lane < deg) ? d : -1);
        nbr_i[d * KNBR + lane] = e;
    }
    if (lane == 0) { out_deg[d] = (float)deg; deg_i[d] = deg; }
    if (lane < 3)  out_coord[d * 3 + lane] = coord[id * 3 + lane];
    if (lane == 3) out_batch[d] = (float)batch[id];
}

// K6: scatter-mean of gathered features. One block per dst, one thread per feature dim.
__global__ void agg_kernel(const float* __restrict__ feat,
                           const int* __restrict__ nbr_i, const int* __restrict__ deg_i,
                           int F, float* __restrict__ out_feat) {
    const int d = blockIdx.x;
    const int t = threadIdx.x;  // F threads
    const int deg = deg_i[d];
    float acc = 0.0f;
    for (int k = 0; k < deg; ++k) {
        int nb = nbr_i[d * KNBR + k];
        acc = __fadd_rn(acc, feat[nb * F + t]);
    }
    float den = (float)(deg > 0 ? deg : 1);
    out_feat[d * F + t] = acc / den;
}

extern "C" void kernel_launch(void* const* d_in, const int* in_sizes, int n_in,
                              void* d_out, int out_size, void* d_ws, size_t ws_size,
                              hipStream_t stream) {
    const float* coord = (const float*)d_in[0];
    const float* feat  = (const float*)d_in[1];
    const int*   batch = (const int*)d_in[2];

    const int N     = in_sizes[0] / 3;
    const int F     = in_sizes[1] / N;
    const int n_dst = N / 4;            // RATIO = 0.25

    // workspace layout
    float* sx = (float*)d_ws;
    float* sy = sx + N;
    float* sz = sy + N;
    float* sn = sz + N;
    float* rx = sn + N;
    float* ry = rx + N;
    float* rz = ry + N;
    int*   rorig     = (int*)(rz + N);
    int*   cell      = rorig + N;
    int*   rank      = cell + N;
    int*   hist      = rank + N;
    int*   cellstart = hist + NCELL;
    int*   idx       = cellstart + NCELL;
    int*   nbr_i     = idx + n_dst;
    int*   deg_i     = nbr_i + n_dst * KNBR;

    // output layout (all written as float32), reference return order
    float* out     = (float*)d_out;
    float* o_coord = out;                         // n_dst*3
    float* o_feat  = o_coord + (size_t)n_dst * 3; // n_dst*F
    float* o_esrc  = o_feat  + (size_t)n_dst * F; // n_dst*K
    float* o_edst  = o_esrc  + (size_t)n_dst * KNBR;
    float* o_deg   = o_edst  + (size_t)n_dst * KNBR;
    float* o_batch = o_deg   + n_dst;

    hipMemsetAsync(hist, 0, NCELL * sizeof(int), stream);
    prep_kernel<<<(N + 255) / 256, 256, 0, stream>>>(coord, N, sx, sy, sz, sn,
                                                     cell, rank, hist);
    scan_kernel<<<1, 1024, 0, stream>>>(hist, cellstart);
    scatter_kernel<<<(N + 255) / 256, 256, 0, stream>>>(sx, sy, sz, cell, rank,
                                                        cellstart, N, rx, ry, rz, rorig);
    fps_kernel<<<1, FT, 0, stream>>>(rx, ry, rz, rorig, sx, sy, sz, N, n_dst, idx);
    ball_kernel<<<n_dst, 64, 0, stream>>>(sx, sy, sz, sn, idx, coord, batch, N, n_dst,
                                          o_coord, o_esrc, o_edst, o_deg, o_batch,
                                          nbr_i, deg_i);
    agg_kernel<<<n_dst, F, 0, stream>>>(feat, nbr_i, deg_i, F, o_feat);
}

// Round 4
// 21012.793 us; speedup vs baseline: 2.0527x; 2.0527x over previous
//
#include <hip/hip_runtime.h>

#define KNBR 32
#define NCELL 4096      // 16^3 Morton cells
#define FT 1024         // fps threads
#define FP 20           // points per fps thread
#define FPQ (FP / 4)    // float4 groups per thread
#define FCAP (FT * FP)  // padded point capacity (20480)

// Reference-matching squared distance: ((dx*dx + dy*dy) + dz*dz), no FMA contraction.
__device__ __forceinline__ float sq_dist_nofma(float px, float py, float pz,
                                               float cx, float cy, float cz) {
    float dx = __fsub_rn(px, cx);
    float dy = __fsub_rn(py, cy);
    float dz = __fsub_rn(pz, cz);
    return __fadd_rn(__fadd_rn(__fmul_rn(dx, dx), __fmul_rn(dy, dy)), __fmul_rn(dz, dz));
}

__device__ __forceinline__ unsigned spread4(unsigned v) {
    return (v & 1u) | ((v & 2u) << 2) | ((v & 4u) << 4) | ((v & 8u) << 6);
}

// K1: AoS -> SoA + norms + Morton cell id + within-cell rank (counting-sort pass 1)
__global__ void prep_kernel(const float* __restrict__ coord, int N,
                            float* __restrict__ sx, float* __restrict__ sy,
                            float* __restrict__ sz, float* __restrict__ sn,
                            int* __restrict__ cell, int* __restrict__ rank,
                            int* __restrict__ hist) {
    int i = blockIdx.x * blockDim.x + threadIdx.x;
    if (i < N) {
        float x = coord[3 * i + 0];
        float y = coord[3 * i + 1];
        float z = coord[3 * i + 2];
        sx[i] = x; sy[i] = y; sz[i] = z;
        sn[i] = __fadd_rn(__fadd_rn(__fmul_rn(x, x), __fmul_rn(y, y)), __fmul_rn(z, z));
        int ix = (int)(x * 16.0f); ix = ix < 0 ? 0 : (ix > 15 ? 15 : ix);
        int iy = (int)(y * 16.0f); iy = iy < 0 ? 0 : (iy > 15 ? 15 : iy);
        int iz = (int)(z * 16.0f); iz = iz < 0 ? 0 : (iz > 15 ? 15 : iz);
        unsigned mc = spread4(ix) | (spread4(iy) << 1) | (spread4(iz) << 2);
        cell[i] = (int)mc;
        rank[i] = atomicAdd(&hist[mc], 1);
    }
}

// K2: exclusive scan of 4096-bin histogram
__global__ __launch_bounds__(1024) void scan_kernel(const int* __restrict__ hist,
                                                    int* __restrict__ cellstart) {
    __shared__ int buf[1024];
    int t = threadIdx.x;
    int h0 = hist[4 * t], h1 = hist[4 * t + 1], h2 = hist[4 * t + 2], h3 = hist[4 * t + 3];
    int s = h0 + h1 + h2 + h3;
    buf[t] = s;
    __syncthreads();
    for (int off = 1; off < 1024; off <<= 1) {
        int v = (t >= off) ? buf[t - off] : 0;
        __syncthreads();
        buf[t] += v;
        __syncthreads();
    }
    int ex = buf[t] - s;
    cellstart[4 * t]     = ex;
    cellstart[4 * t + 1] = ex + h0;
    cellstart[4 * t + 2] = ex + h0 + h1;
    cellstart[4 * t + 3] = ex + h0 + h1 + h2;
}

// K3: scatter into Morton order (counting-sort pass 2)
__global__ void scatter_kernel(const float* __restrict__ sx, const float* __restrict__ sy,
                               const float* __restrict__ sz,
                               const int* __restrict__ cell, const int* __restrict__ rank,
                               const int* __restrict__ cellstart, int N,
                               float* __restrict__ rx, float* __restrict__ ry,
                               float* __restrict__ rz, int* __restrict__ rorig) {
    int i = blockIdx.x * blockDim.x + threadIdx.x;
    if (i < N) {
        int pos = cellstart[cell[i]] + rank[i];
        rx[pos] = sx[i]; ry[pos] = sy[i]; rz[pos] = sz[i];
        rorig[pos] = i;
    }
}

// K3b: pad [N, FCAP) with sentinels so fps can do branchless float4 loads
__global__ void pad_kernel(float* __restrict__ rx, float* __restrict__ ry,
                           float* __restrict__ rz, int* __restrict__ rorig,
                           int N, int cap) {
    int i = N + blockIdx.x * blockDim.x + threadIdx.x;
    if (i < cap) { rx[i] = 1e18f; ry[i] = 1e18f; rz[i] = 1e18f; rorig[i] = 0x7fffffff; }
}

// K4: FPS. Registers hold only RMW state (md, og); coords re-read from L1/L2 as float4.
// Spatial prune: thread skips its whole update when (D - r_t)^2 > max md (conservative).
// Single barrier per step: owner lane writes (v, i, x, y, z); all threads pick winner.
#define INIT_PT(j, PX, PY, PZ, OI)                                                       \
    {                                                                                    \
        og[j] = (OI);                                                                    \
        bool real = (base + (j) < N);                                                    \
        float d = sq_dist_nofma((PX), (PY), (PZ), c0x, c0y, c0z);                        \
        float m = real ? d : -3e38f;                                                     \
        md[j] = m;                                                                       \
        if (m > bv || (m == bv && og[j] < bi)) {                                         \
            bv = m; bi = og[j]; bx = (PX); by = (PY); bz = (PZ);                         \
        }                                                                                \
        if (real) {                                                                      \
            mnx = fminf(mnx, (PX)); mxx = fmaxf(mxx, (PX));                              \
            mny = fminf(mny, (PY)); mxy = fmaxf(mxy, (PY));                              \
            mnz = fminf(mnz, (PZ)); mxz = fmaxf(mxz, (PZ));                              \
        }                                                                                \
    }

#define UPD_PT(j, PX, PY, PZ)                                                            \
    {                                                                                    \
        float d = sq_dist_nofma((PX), (PY), (PZ), ncx, ncy, ncz);                        \
        float m = fminf(md[j], d);                                                       \
        md[j] = m;                                                                       \
        if (m > bv || (m == bv && og[j] < bi)) {                                         \
            bv = m; bi = og[j]; bx = (PX); by = (PY); bz = (PZ);                         \
        }                                                                                \
    }

__global__ __launch_bounds__(FT, 4)
void fps_kernel(const float* __restrict__ rx, const float* __restrict__ ry,
                const float* __restrict__ rz, const int* __restrict__ rorig,
                const float* __restrict__ sx, const float* __restrict__ sy,
                const float* __restrict__ sz,
                int N, int n_dst, int* __restrict__ out_idx) {
    const int NW = FT / 64;
    __shared__ float tup[2][NW][8];   // [parity][wave][v, i(bits), x, y, z]

    const int tid  = threadIdx.x;
    const int wv   = tid >> 6;
    const int base = tid * FP;
    int npts = N - base; npts = npts < 0 ? 0 : (npts > FP ? FP : npts);

    const float4* rx4 = (const float4*)rx + tid * FPQ;
    const float4* ry4 = (const float4*)ry + tid * FPQ;
    const float4* rz4 = (const float4*)rz + tid * FPQ;
    const int4*   ro4 = (const int4*)rorig + tid * FPQ;

    float md[FP]; int og[FP];

    const float c0x = sx[0], c0y = sy[0], c0z = sz[0];
    float mnx = 1e30f, mny = 1e30f, mnz = 1e30f, mxx = -1e30f, mxy = -1e30f, mxz = -1e30f;
    float bv = -3e38f, bx = 0.f, by = 0.f, bz = 0.f; int bi = 0x7fffffff;

    #pragma unroll
    for (int q = 0; q < FPQ; ++q) {
        float4 X = rx4[q], Y = ry4[q], Z = rz4[q];
        int4   I = ro4[q];
        INIT_PT(4 * q + 0, X.x, Y.x, Z.x, I.x);
        INIT_PT(4 * q + 1, X.y, Y.y, Z.y, I.y);
        INIT_PT(4 * q + 2, X.z, Y.z, Z.z, I.z);
        INIT_PT(4 * q + 3, X.w, Y.w, Z.w, I.w);
    }

    // bounding sphere (conservative)
    float ctx = 0.5f * (mnx + mxx), cty = 0.5f * (mny + mxy), ctz = 0.5f * (mnz + mxz);
    float rt = 0.f;
    if (npts > 0) {
        float ex = fmaxf(mxx - ctx, ctx - mnx);
        float ey = fmaxf(mxy - cty, cty - mny);
        float ez = fmaxf(mxz - ctz, ctz - mnz);
        rt = sqrtf(ex * ex + ey * ey + ez * ez) * 1.0001f + 1e-7f;
    }
    float thr2 = -1.f;
    if (npts > 0) { float t0 = sqrtf(fmaxf(bv, 0.f)) * 1.0001f + rt; thr2 = t0 * t0 * 1.0002f + 1e-12f; }
    if (tid == 0) out_idx[0] = 0;

    int par = 0;
    for (int s = 1; s < n_dst; ++s) {
        // wave argmax of (bv, bi), first-original-index tie-break
        float v = bv; int i = bi;
        #pragma unroll
        for (int off = 32; off; off >>= 1) {
            float v2 = __shfl_xor(v, off, 64);
            int   i2 = __shfl_xor(i, off, 64);
            if (v2 > v || (v2 == v && i2 < i)) { v = v2; i = i2; }
        }
        if (bi == i) {   // owner lane (unique real og; empty waves write identical tuples)
            tup[par][wv][0] = v;
            tup[par][wv][1] = __int_as_float(i);
            tup[par][wv][2] = bx; tup[par][wv][3] = by; tup[par][wv][4] = bz;
        }
        __syncthreads();
        float Wv = -3e38f; int Wi = 0x7fffffff; int Ww = 0;
        #pragma unroll
        for (int w = 0; w < NW; ++w) {
            float tv = tup[par][w][0];
            int   ti = __float_as_int(tup[par][w][1]);
            if (tv > Wv || (tv == Wv && ti < Wi)) { Wv = tv; Wi = ti; Ww = w; }
        }
        float ncx = tup[par][Ww][2], ncy = tup[par][Ww][3], ncz = tup[par][Ww][4];
        if (tid == 0) out_idx[s] = Wi;
        par ^= 1;   // double-buffered tuples: no second barrier needed

        // spatial prune: skip whole thread when no md can decrease (thr2=-1 for empty threads)
        float Dx = ncx - ctx, Dy = ncy - cty, Dz = ncz - ctz;
        float D2 = Dx * Dx + Dy * Dy + Dz * Dz;
        if (D2 <= thr2) {
            bv = -3e38f; bi = 0x7fffffff;
            #pragma unroll
            for (int q = 0; q < FPQ; ++q) {
                float4 X = rx4[q], Y = ry4[q], Z = rz4[q];
                UPD_PT(4 * q + 0, X.x, Y.x, Z.x);
                UPD_PT(4 * q + 1, X.y, Y.y, Z.y);
                UPD_PT(4 * q + 2, X.z, Y.z, Z.z);
                UPD_PT(4 * q + 3, X.w, Y.w, Z.w);
            }
            float t0 = sqrtf(fmaxf(bv, 0.f)) * 1.0001f + rt;
            thr2 = t0 * t0 * 1.0002f + 1e-12f;
        }
        // pruned threads keep valid (bv, bi, bx, by, bz, thr2): md provably unchanged
    }
}

// K5: ball query, one wave per dst. First K in-radius src indices in ascending order.
__global__ void ball_kernel(const float* __restrict__ sx, const float* __restrict__ sy,
                            const float* __restrict__ sz, const float* __restrict__ sn,
                            const int* __restrict__ idx,
                            const float* __restrict__ coord, const int* __restrict__ batch,
                            int N, int n_dst,
                            float* __restrict__ out_coord, float* __restrict__ out_esrc,
                            float* __restrict__ out_edst, float* __restrict__ out_deg,
                            float* __restrict__ out_batch,
                            int* __restrict__ nbr_i, int* __restrict__ deg_i) {
    const int d    = blockIdx.x;
    const int lane = threadIdx.x;   // block of 64
    __shared__ int nbr[KNBR];

    const int id = idx[d];
    const float cx = sx[id], cy = sy[id], cz = sz[id];
    const float dn = sn[id];
    const float RR = (float)(0.08 * 0.08);

    int cnt = 0;
    for (int base = 0; base < N && cnt < KNBR; base += 64) {
        int i = base + lane;
        bool in = false;
        if (i < N) {
            float t     = __fmul_rn(sx[i], cx);
            float inner = __fmaf_rn(sy[i], cy, t);
            inner       = __fmaf_rn(sz[i], cz, inner);
            float d2    = __fsub_rn(__fadd_rn(dn, sn[i]), __fmul_rn(2.0f, inner));
            in = (d2 <= RR);
        }
        unsigned long long m = __ballot(in);
        int pos = cnt + __popcll(m & ((1ull << lane) - 1ull));
        if (in && pos < KNBR) nbr[pos] = i;
        cnt += (int)__popcll(m);
    }
    __syncthreads();

    int deg = cnt < KNBR ? cnt : KNBR;
    if (lane < KNBR) {
        int e = (lane < deg) ? nbr[lane] : -1;
        out_esrc[d * KNBR + lane] = (float)e;
        out_edst[d * KNBR + lane] = (float)((lane < deg) ? d : -1);
        nbr_i[d * KNBR + lane] = e;
    }
    if (lane == 0) { out_deg[d] = (float)deg; deg_i[d] = deg; }
    if (lane < 3)  out_coord[d * 3 + lane] = coord[id * 3 + lane];
    if (lane == 3) out_batch[d] = (float)batch[id];
}

// K6: scatter-mean of gathered features. One block per dst, one thread per feature dim.
__global__ void agg_kernel(const float* __restrict__ feat,
                           const int* __restrict__ nbr_i, const int* __restrict__ deg_i,
                           int F, float* __restrict__ out_feat) {
    const int d = blockIdx.x;
    const int t = threadIdx.x;  // F threads
    const int deg = deg_i[d];
    float acc = 0.0f;
    for (int k = 0; k < deg; ++k) {
        int nb = nbr_i[d * KNBR + k];
        acc = __fadd_rn(acc, feat[nb * F + t]);
    }
    float den = (float)(deg > 0 ? deg : 1);
    out_feat[d * F + t] = acc / den;
}

extern "C" void kernel_launch(void* const* d_in, const int* in_sizes, int n_in,
                              void* d_out, int out_size, void* d_ws, size_t ws_size,
                              hipStream_t stream) {
    const float* coord = (const float*)d_in[0];
    const float* feat  = (const float*)d_in[1];
    const int*   batch = (const int*)d_in[2];

    const int N     = in_sizes[0] / 3;
    const int F     = in_sizes[1] / N;
    const int n_dst = N / 4;            // RATIO = 0.25

    // workspace layout (rx 16B-aligned: 4N floats precede it, N=20000 -> 320000 B)
    float* sx = (float*)d_ws;
    float* sy = sx + N;
    float* sz = sy + N;
    float* sn = sz + N;
    float* rx = sn + N;
    float* ry = rx + FCAP;
    float* rz = ry + FCAP;
    int*   rorig     = (int*)(rz + FCAP);
    int*   cell      = rorig + FCAP;
    int*   rank      = cell + N;
    int*   hist      = rank + N;
    int*   cellstart = hist + NCELL;
    int*   idx       = cellstart + NCELL;
    int*   nbr_i     = idx + n_dst;
    int*   deg_i     = nbr_i + n_dst * KNBR;

    // output layout (all float32), reference return order
    float* out     = (float*)d_out;
    float* o_coord = out;                         // n_dst*3
    float* o_feat  = o_coord + (size_t)n_dst * 3; // n_dst*F
    float* o_esrc  = o_feat  + (size_t)n_dst * F; // n_dst*K
    float* o_edst  = o_esrc  + (size_t)n_dst * KNBR;
    float* o_deg   = o_edst  + (size_t)n_dst * KNBR;
    float* o_batch = o_deg   + n_dst;

    hipMemsetAsync(hist, 0, NCELL * sizeof(int), stream);
    prep_kernel<<<(N + 255) / 256, 256, 0, stream>>>(coord, N, sx, sy, sz, sn,
                                                     cell, rank, hist);
    scan_kernel<<<1, 1024, 0, stream>>>(hist, cellstart);
    scatter_kernel<<<(N + 255) / 256, 256, 0, stream>>>(sx, sy, sz, cell, rank,
                                                        cellstart, N, rx, ry, rz, rorig);
    pad_kernel<<<(FCAP - N + 255) / 256, 256, 0, stream>>>(rx, ry, rz, rorig, N, FCAP);
    fps_kernel<<<1, FT, 0, stream>>>(rx, ry, rz, rorig, sx, sy, sz, N, n_dst, idx);
    ball_kernel<<<n_dst, 64, 0, stream>>>(sx, sy, sz, sn, idx, coord, batch, N, n_dst,
                                          o_coord, o_esrc, o_edst, o_deg, o_batch,
                                          nbr_i, deg_i);
    agg_kernel<<<n_dst, F, 0, stream>>>(feat, nbr_i, deg_i, F, o_feat);
}